// Round 8
// baseline (186.231 us; speedup 1.0000x reference)
//
#include <hip/hip_runtime.h>
#include <hip/hip_bf16.h>
#include <stdint.h>

#define AS1 __attribute__((address_space(1)))
#define AS3 __attribute__((address_space(3)))

typedef __bf16 bf16x8 __attribute__((ext_vector_type(8)));
typedef float  f32x4  __attribute__((ext_vector_type(4)));
typedef unsigned short ushort8v __attribute__((ext_vector_type(8)));
typedef unsigned short ushort4v __attribute__((ext_vector_type(4)));
typedef short short8v __attribute__((ext_vector_type(8)));
typedef short short4v __attribute__((ext_vector_type(4)));

__device__ __forceinline__ unsigned short f2bf(float f) {
    unsigned int u = __float_as_uint(f);
    u += 0x7fffu + ((u >> 16) & 1u);           // round-to-nearest-even
    return (unsigned short)(u >> 16);
}
__device__ __forceinline__ unsigned int pk2bf(float a, float b) {
    __hip_bfloat162 h = __float22bfloat162_rn(make_float2(a, b));  // x->low short
    unsigned int u;
    __builtin_memcpy(&u, &h, 4);
    return u;
}
__device__ __forceinline__ void g2lds16(const void* gp, void* lp) {
    __builtin_amdgcn_global_load_lds((AS1 void*)gp, (AS3 void*)lp, 16, 0, 0);
}
#define E2(x) __builtin_amdgcn_exp2f(x)

// ---------------- cast fp32 -> bf16 (x, Wq, Wk, Wv in one launch) -----------
__global__ __launch_bounds__(256) void cast_all(const float* __restrict__ x,
                                                const float* __restrict__ w0,
                                                const float* __restrict__ w1,
                                                const float* __restrict__ w2,
                                                unsigned short* __restrict__ xb,
                                                unsigned short* __restrict__ wc) {
    int id = blockIdx.x;
    const float* s;
    unsigned short* d;
    int base;
    if (id < 4096) { s = x; d = xb; base = id; }
    else {
        int z = (id - 4096) >> 10;
        s = (z == 0) ? w0 : (z == 1) ? w1 : w2;
        d = wc + (size_t)z * 1048576;
        base = (id - 4096) & 1023;
    }
    int i = (base * 256 + threadIdx.x) * 4;
    float4 v = *(const float4*)(s + i);
    ushort4v o = { f2bf(v.x), f2bf(v.y), f2bf(v.z), f2bf(v.w) };
    *(ushort4v*)(d + i) = o;
}

// ---------------- QKV GEMM: out = X @ W^T (NT), m97 structure (BK=32) --------
// Q (z=0) pre-scaled by 0.125*log2(e) so attn can exp2 scores directly.
__global__ __launch_bounds__(256) void gemm_qkv(const unsigned short* __restrict__ X,
                                                const unsigned short* __restrict__ W,
                                                unsigned short* __restrict__ QKV) {
    const int K = 1024, N = 1024;
    const int z = blockIdx.z;
    const unsigned short* A = X;
    const unsigned short* B = W + (size_t)z * (1024 * 1024);
    unsigned short* C = QKV + (size_t)z * (4096 * 1024);
    const float qs = (z == 0) ? 0.18033688011112042f : 1.0f;

    const int m0 = blockIdx.y * 128;
    const int n0 = blockIdx.x * 128;

    __shared__ unsigned short As[128 * 32];
    __shared__ unsigned short Bs[128 * 32];

    const int t = threadIdx.x;
    const int w = t >> 6;
    const int l = t & 63;
    const int wm = (w >> 1) * 64;
    const int wn = (w & 1) * 64;
    const int cl = l & 15;
    const int quad = l >> 4;

    const int srow = w * 16 + (l >> 2);
    const int scol = (l & 3) * 8;

    f32x4 acc[4][4] = {};

    for (int k0 = 0; k0 < K; k0 += 32) {
        g2lds16(A + (size_t)(m0 + srow) * K + k0 + scol,      As + w * 512);
        g2lds16(A + (size_t)(m0 + 64 + srow) * K + k0 + scol, As + 2048 + w * 512);
        g2lds16(B + (size_t)(n0 + srow) * K + k0 + scol,      Bs + w * 512);
        g2lds16(B + (size_t)(n0 + 64 + srow) * K + k0 + scol, Bs + 2048 + w * 512);
        __syncthreads();

        bf16x8 af[4], bfr[4];
        #pragma unroll
        for (int i = 0; i < 4; ++i)
            af[i] = *(const bf16x8*)(As + (wm + i * 16 + cl) * 32 + quad * 8);
        #pragma unroll
        for (int j = 0; j < 4; ++j)
            bfr[j] = *(const bf16x8*)(Bs + (wn + j * 16 + cl) * 32 + quad * 8);
        #pragma unroll
        for (int i = 0; i < 4; ++i)
            #pragma unroll
            for (int j = 0; j < 4; ++j)
                acc[i][j] = __builtin_amdgcn_mfma_f32_16x16x32_bf16(af[i], bfr[j], acc[i][j], 0, 0, 0);
        __syncthreads();
    }

    #pragma unroll
    for (int i = 0; i < 4; ++i) {
        #pragma unroll
        for (int r = 0; r < 4; ++r) {
            size_t row = (size_t)(m0 + wm + i * 16 + quad * 4 + r);
            #pragma unroll
            for (int j = 0; j < 4; ++j)
                C[row * N + (n0 + wn + j * 16 + cl)] = f2bf(acc[i][j][r] * qs);
        }
    }
}

// ---------------- V swizzle to VT3 (per bh) ---------------------------------
// VT3 element (tau, d) at (tau>>4)*1024 + (d&15)*64 + ((tau>>2)&3)*16
//                        + (d>>4)*4 + (tau&3)
__global__ __launch_bounds__(256) void vtrans(const unsigned short* __restrict__ Vn,
                                              unsigned short* __restrict__ V3) {
    const int bh = blockIdx.y;
    const int T0 = blockIdx.x * 128;
    __shared__ unsigned short L[128 * 72];
    const int t = threadIdx.x;

    const unsigned short* src = Vn + (size_t)bh * 131072 + (size_t)T0 * 64;
    #pragma unroll
    for (int p = 0; p < 4; ++p) {
        int r = p * 32 + (t >> 3), c = (t & 7) * 8;
        *(ushort8v*)(L + r * 72 + c) = *(const ushort8v*)(src + (size_t)r * 64 + c);
    }
    __syncthreads();
    unsigned short* dst = V3 + (size_t)bh * 131072 + (size_t)(T0 >> 4) * 1024;
    #pragma unroll
    for (int p = 0; p < 2; ++p) {
        int item = p * 256 + t;                 // 512 items: kb(8) x cl(16) x qk(4)
        int kb = item >> 6, cl = (item >> 2) & 15, qk = item & 3;
        ushort8v a, b;
        #pragma unroll
        for (int u = 0; u < 8; ++u) {
            int dt = u >> 2, j = u & 3;
            a[u] = L[(kb * 16 + qk * 4 + j) * 72 + dt * 16 + cl];
            b[u] = L[(kb * 16 + qk * 4 + j) * 72 + (dt + 2) * 16 + cl];
        }
        unsigned short* dp = dst + kb * 1024 + cl * 64 + qk * 16;
        *(ushort8v*)(dp) = a;
        *(ushort8v*)(dp + 8) = b;
    }
}

// ---------------- Flash attention: balanced strip-pairs, 4-way kv-split ------
// Block (256 thr) owns strips (s, 63-s): 65 chunk-units per block, uniform.
// Waves split a strip's 32-kv chunks mod 4 (softmax associative, no running
// max); one LDS combine per strip. Register-resident P (S^T C-layout ==
// 16x16x16 B-frag); V^T via VT3 b128. XCD-pinned: 4 bh per XCD.
// __launch_bounds__(256,3): VGPR cap ~170 so BOTH KV buffers stay live across
// chunk_body — at R7's 112-cap the allocator sank the prefetch loads to their
// uses (no overlap, full latency per chunk). Prefetch index is clamped and
// loaded unconditionally so it cannot be sunk behind a branch.
struct KVf { bf16x8 k[4]; short8v v[4]; };

__device__ __forceinline__ void load_kv(const unsigned short* Kb, const unsigned short* Vb,
                                        int kv0, int cl, int quad, KVf& f) {
    const unsigned short* ka = Kb + (size_t)(kv0 + cl) * 64 + quad * 8;
    f.k[0] = *(const bf16x8*)(ka);                 // kt=0 dh=0
    f.k[1] = *(const bf16x8*)(ka + 32);            // kt=0 dh=1
    f.k[2] = *(const bf16x8*)(ka + 16 * 64);       // kt=1 dh=0
    f.k[3] = *(const bf16x8*)(ka + 16 * 64 + 32);  // kt=1 dh=1
    const unsigned short* va = Vb + (size_t)(kv0 >> 4) * 1024 + cl * 64 + quad * 16;
    f.v[0] = *(const short8v*)(va);                // kt=0 dt=0,1
    f.v[1] = *(const short8v*)(va + 8);            // kt=0 dt=2,3
    f.v[2] = *(const short8v*)(va + 1024);         // kt=1 dt=0,1
    f.v[3] = *(const short8v*)(va + 1024 + 8);     // kt=1 dt=2,3
}

__device__ __forceinline__ void chunk_body(const KVf& f, const bf16x8 qf[2][2],
                                           f32x4 o[2][4], float lp[2],
                                           int cl, int quad, bool masked) {
    // S^T tiles st[kt][mt]: lane holds (kv = kt*16+quad*4+r, m = mt*16+cl)
    f32x4 st[2][2] = {};
    #pragma unroll
    for (int kt = 0; kt < 2; ++kt)
        #pragma unroll
        for (int mt = 0; mt < 2; ++mt) {
            st[kt][mt] = __builtin_amdgcn_mfma_f32_16x16x32_bf16(f.k[kt * 2],     qf[mt][0], st[kt][mt], 0, 0, 0);
            st[kt][mt] = __builtin_amdgcn_mfma_f32_16x16x32_bf16(f.k[kt * 2 + 1], qf[mt][1], st[kt][mt], 0, 0, 0);
        }

    short4v pb[2][2];
    #pragma unroll
    for (int kt = 0; kt < 2; ++kt)
        #pragma unroll
        for (int mt = 0; mt < 2; ++mt) {
            float p0, p1, p2, p3;
            if (masked) {
                int lm = mt * 16 + cl, lk = kt * 16 + quad * 4;
                p0 = (lk     <= lm) ? E2(st[kt][mt][0]) : 0.f;
                p1 = (lk + 1 <= lm) ? E2(st[kt][mt][1]) : 0.f;
                p2 = (lk + 2 <= lm) ? E2(st[kt][mt][2]) : 0.f;
                p3 = (lk + 3 <= lm) ? E2(st[kt][mt][3]) : 0.f;
            } else {
                p0 = E2(st[kt][mt][0]);
                p1 = E2(st[kt][mt][1]);
                p2 = E2(st[kt][mt][2]);
                p3 = E2(st[kt][mt][3]);
            }
            lp[mt] += (p0 + p1) + (p2 + p3);
            uint2 u = { pk2bf(p0, p1), pk2bf(p2, p3) };
            short4v pv;
            __builtin_memcpy(&pv, &u, 8);
            pb[kt][mt] = pv;
        }

    // O^T tiles o[mt][dt] += V^T(dt,kt) . P^T(kt,mt)  (16x16x16, K=16)
    #pragma unroll
    for (int mt = 0; mt < 2; ++mt)
        #pragma unroll
        for (int dt = 0; dt < 4; ++dt) {
            #pragma unroll
            for (int kt = 0; kt < 2; ++kt) {
                short8v vv = f.v[kt * 2 + (dt >> 1)];
                short4v va = (dt & 1)
                    ? __builtin_shufflevector(vv, vv, 4, 5, 6, 7)
                    : __builtin_shufflevector(vv, vv, 0, 1, 2, 3);
                o[mt][dt] = __builtin_amdgcn_mfma_f32_16x16x16bf16_1k(va, pb[kt][mt], o[mt][dt], 0, 0, 0);
            }
        }
}

__global__ __launch_bounds__(256, 3) void attn(const unsigned short* __restrict__ QK,
                                               const unsigned short* __restrict__ V3,
                                               float* __restrict__ Out) {
    const int id = blockIdx.x;
    const int bh = (id & 7) * 4 + ((id >> 3) & 3);     // 4 bh per XCD
    const int pr = id >> 5;                            // strip-pair 0..31
    const int w = threadIdx.x >> 6;                    // kv-split lane 0..3
    const int l = threadIdx.x & 63;
    const int cl = l & 15;
    const int quad = l >> 4;

    const size_t bhoff = (size_t)bh * 131072;
    const unsigned short* Qb = QK + bhoff;
    const unsigned short* Kb = QK + (size_t)4194304 + bhoff;
    const unsigned short* Vb = V3 + bhoff;
    float* Ob = Out + bhoff;

    __shared__ float Ored[3][64][34];                  // partials of waves 1..3

    #pragma unroll 1
    for (int half = 0; half < 2; ++half) {
        const int s = half ? (63 - pr) : pr;
        const int m0 = s * 32;
        const int nch = s + 1;                         // 32-kv chunks total
        const int clast = nch - 1;

        bf16x8 qf[2][2];
        #pragma unroll
        for (int mt = 0; mt < 2; ++mt) {
            const unsigned short* qa = Qb + (size_t)(m0 + mt * 16 + cl) * 64 + quad * 8;
            qf[mt][0] = *(const bf16x8*)(qa);
            qf[mt][1] = *(const bf16x8*)(qa + 32);
        }

        f32x4 o[2][4] = {};
        float lp[2] = {0.f, 0.f};

        const int nmine = (nch > w) ? ((nch - w + 3) >> 2) : 0;  // c = w, w+4, ...
        if (nmine > 0) {
            KVf fA, fB;
            load_kv(Kb, Vb, w * 32, cl, quad, fA);
            int c = w, i = 0;
            for (;;) {
                int cn = (c + 4 > clast) ? clast : (c + 4);   // clamped, unconditional
                load_kv(Kb, Vb, cn * 32, cl, quad, fB);
                chunk_body(fA, qf, o, lp, cl, quad, c == clast);
                if (++i >= nmine) break;
                c += 4;
                int cn2 = (c + 4 > clast) ? clast : (c + 4);
                load_kv(Kb, Vb, cn2 * 32, cl, quad, fA);
                chunk_body(fB, qf, o, lp, cl, quad, c == clast);
                if (++i >= nmine) break;
                c += 4;
            }
        }

        // quad-reduce lp (lanes sharing cl hold disjoint kv subsets)
        #pragma unroll
        for (int mt = 0; mt < 2; ++mt) {
            lp[mt] += __shfl_xor(lp[mt], 16);
            lp[mt] += __shfl_xor(lp[mt], 32);
        }

        // 4-way cross-wave combine (plain partial sums)
        if (w > 0) {
            float* row = &Ored[w - 1][l][0];
            #pragma unroll
            for (int mt = 0; mt < 2; ++mt)
                #pragma unroll
                for (int dt = 0; dt < 4; ++dt)
                    *(f32x4*)(row + (mt * 4 + dt) * 4) = o[mt][dt];
            row[32] = lp[0];
            row[33] = lp[1];
        }
        __syncthreads();
        if (w == 0) {
            #pragma unroll
            for (int v = 0; v < 3; ++v) {
                const float* row = &Ored[v][l][0];
                #pragma unroll
                for (int mt = 0; mt < 2; ++mt)
                    #pragma unroll
                    for (int dt = 0; dt < 4; ++dt)
                        o[mt][dt] += *(const f32x4*)(row + (mt * 4 + dt) * 4);
                lp[0] += row[32];
                lp[1] += row[33];
            }
            #pragma unroll
            for (int mt = 0; mt < 2; ++mt) {
                float inv = 1.0f / lp[mt];
                #pragma unroll
                for (int dt = 0; dt < 4; ++dt) {
                    f32x4 r = o[mt][dt];
                    r[0] *= inv; r[1] *= inv; r[2] *= inv; r[3] *= inv;
                    *(f32x4*)(Ob + (size_t)(m0 + mt * 16 + cl) * 64 + dt * 16 + quad * 4) = r;
                }
            }
        }
        __syncthreads();                               // Ored reuse across halves
    }
}

extern "C" void kernel_launch(void* const* d_in, const int* in_sizes, int n_in,
                              void* d_out, int out_size, void* d_ws, size_t ws_size,
                              hipStream_t stream) {
    const float* x  = (const float*)d_in[0];
    const float* Wq = (const float*)d_in[1];
    const float* Wk = (const float*)d_in[2];
    const float* Wv = (const float*)d_in[3];
    float* out = (float*)d_out;

    // ws: xb 8MB | wc 6MB | QKV natural 24MB | VT3 8MB = 46MB
    unsigned short* xb  = (unsigned short*)d_ws;
    unsigned short* wc  = xb + (size_t)4096 * 1024;
    unsigned short* qkv = wc + (size_t)3 * 1024 * 1024;
    unsigned short* vt  = qkv + (size_t)3 * 4096 * 1024;

    hipLaunchKernelGGL(cast_all, dim3(7168), dim3(256), 0, stream, x, Wq, Wk, Wv, xb, wc);
    hipLaunchKernelGGL(gemm_qkv, dim3(8, 32, 3), dim3(256), 0, stream, xb, wc, qkv);
    hipLaunchKernelGGL(vtrans, dim3(16, 32), dim3(256), 0, stream, qkv + (size_t)2 * 4096 * 1024, vt);
    hipLaunchKernelGGL(attn, dim3(1024), dim3(256), 0, stream, qkv, vt, out);
}

// Round 9
// 148.016 us; speedup vs baseline: 1.2582x; 1.2582x over previous
//
#include <hip/hip_runtime.h>
#include <hip/hip_bf16.h>
#include <stdint.h>

#define AS1 __attribute__((address_space(1)))
#define AS3 __attribute__((address_space(3)))

typedef __bf16 bf16x8 __attribute__((ext_vector_type(8)));
typedef float  f32x4  __attribute__((ext_vector_type(4)));
typedef unsigned short ushort8v __attribute__((ext_vector_type(8)));
typedef unsigned short ushort4v __attribute__((ext_vector_type(4)));
typedef short short8v __attribute__((ext_vector_type(8)));
typedef short short4v __attribute__((ext_vector_type(4)));

__device__ __forceinline__ unsigned short f2bf(float f) {
    unsigned int u = __float_as_uint(f);
    u += 0x7fffu + ((u >> 16) & 1u);           // round-to-nearest-even
    return (unsigned short)(u >> 16);
}
__device__ __forceinline__ unsigned int pk2bf(float a, float b) {
    __hip_bfloat162 h = __float22bfloat162_rn(make_float2(a, b));  // x->low short
    unsigned int u;
    __builtin_memcpy(&u, &h, 4);
    return u;
}
__device__ __forceinline__ void g2lds16(const void* gp, void* lp) {
    __builtin_amdgcn_global_load_lds((AS1 void*)gp, (AS3 void*)lp, 16, 0, 0);
}
#define E2(x) __builtin_amdgcn_exp2f(x)

// ---------------- cast fp32 -> bf16 (x, Wq, Wk, Wv in one launch) -----------
__global__ __launch_bounds__(256) void cast_all(const float* __restrict__ x,
                                                const float* __restrict__ w0,
                                                const float* __restrict__ w1,
                                                const float* __restrict__ w2,
                                                unsigned short* __restrict__ xb,
                                                unsigned short* __restrict__ wc) {
    int id = blockIdx.x;
    const float* s;
    unsigned short* d;
    int base;
    if (id < 4096) { s = x; d = xb; base = id; }
    else {
        int z = (id - 4096) >> 10;
        s = (z == 0) ? w0 : (z == 1) ? w1 : w2;
        d = wc + (size_t)z * 1048576;
        base = (id - 4096) & 1023;
    }
    int i = (base * 256 + threadIdx.x) * 4;
    float4 v = *(const float4*)(s + i);
    ushort4v o = { f2bf(v.x), f2bf(v.y), f2bf(v.z), f2bf(v.w) };
    *(ushort4v*)(d + i) = o;
}

// ---------------- QKV GEMM: out = X @ W^T (NT), m97 structure (BK=32) --------
// Q (z=0) pre-scaled by 0.125*log2(e) so attn can exp2 scores directly.
__global__ __launch_bounds__(256) void gemm_qkv(const unsigned short* __restrict__ X,
                                                const unsigned short* __restrict__ W,
                                                unsigned short* __restrict__ QKV) {
    const int K = 1024, N = 1024;
    const int z = blockIdx.z;
    const unsigned short* A = X;
    const unsigned short* B = W + (size_t)z * (1024 * 1024);
    unsigned short* C = QKV + (size_t)z * (4096 * 1024);
    const float qs = (z == 0) ? 0.18033688011112042f : 1.0f;

    const int m0 = blockIdx.y * 128;
    const int n0 = blockIdx.x * 128;

    __shared__ unsigned short As[128 * 32];
    __shared__ unsigned short Bs[128 * 32];

    const int t = threadIdx.x;
    const int w = t >> 6;
    const int l = t & 63;
    const int wm = (w >> 1) * 64;
    const int wn = (w & 1) * 64;
    const int cl = l & 15;
    const int quad = l >> 4;

    const int srow = w * 16 + (l >> 2);
    const int scol = (l & 3) * 8;

    f32x4 acc[4][4] = {};

    for (int k0 = 0; k0 < K; k0 += 32) {
        g2lds16(A + (size_t)(m0 + srow) * K + k0 + scol,      As + w * 512);
        g2lds16(A + (size_t)(m0 + 64 + srow) * K + k0 + scol, As + 2048 + w * 512);
        g2lds16(B + (size_t)(n0 + srow) * K + k0 + scol,      Bs + w * 512);
        g2lds16(B + (size_t)(n0 + 64 + srow) * K + k0 + scol, Bs + 2048 + w * 512);
        __syncthreads();

        bf16x8 af[4], bfr[4];
        #pragma unroll
        for (int i = 0; i < 4; ++i)
            af[i] = *(const bf16x8*)(As + (wm + i * 16 + cl) * 32 + quad * 8);
        #pragma unroll
        for (int j = 0; j < 4; ++j)
            bfr[j] = *(const bf16x8*)(Bs + (wn + j * 16 + cl) * 32 + quad * 8);
        #pragma unroll
        for (int i = 0; i < 4; ++i)
            #pragma unroll
            for (int j = 0; j < 4; ++j)
                acc[i][j] = __builtin_amdgcn_mfma_f32_16x16x32_bf16(af[i], bfr[j], acc[i][j], 0, 0, 0);
        __syncthreads();
    }

    #pragma unroll
    for (int i = 0; i < 4; ++i) {
        #pragma unroll
        for (int r = 0; r < 4; ++r) {
            size_t row = (size_t)(m0 + wm + i * 16 + quad * 4 + r);
            #pragma unroll
            for (int j = 0; j < 4; ++j)
                C[row * N + (n0 + wn + j * 16 + cl)] = f2bf(acc[i][j][r] * qs);
        }
    }
}

// ---------------- V swizzle to VT3 (per bh) ---------------------------------
// VT3 element (tau, d) at (tau>>4)*1024 + (d&15)*64 + ((tau>>2)&3)*16
//                        + (d>>4)*4 + (tau&3)
__global__ __launch_bounds__(256) void vtrans(const unsigned short* __restrict__ Vn,
                                              unsigned short* __restrict__ V3) {
    const int bh = blockIdx.y;
    const int T0 = blockIdx.x * 128;
    __shared__ unsigned short L[128 * 72];
    const int t = threadIdx.x;

    const unsigned short* src = Vn + (size_t)bh * 131072 + (size_t)T0 * 64;
    #pragma unroll
    for (int p = 0; p < 4; ++p) {
        int r = p * 32 + (t >> 3), c = (t & 7) * 8;
        *(ushort8v*)(L + r * 72 + c) = *(const ushort8v*)(src + (size_t)r * 64 + c);
    }
    __syncthreads();
    unsigned short* dst = V3 + (size_t)bh * 131072 + (size_t)(T0 >> 4) * 1024;
    #pragma unroll
    for (int p = 0; p < 2; ++p) {
        int item = p * 256 + t;                 // 512 items: kb(8) x cl(16) x qk(4)
        int kb = item >> 6, cl = (item >> 2) & 15, qk = item & 3;
        ushort8v a, b;
        #pragma unroll
        for (int u = 0; u < 8; ++u) {
            int dt = u >> 2, j = u & 3;
            a[u] = L[(kb * 16 + qk * 4 + j) * 72 + dt * 16 + cl];
            b[u] = L[(kb * 16 + qk * 4 + j) * 72 + (dt + 2) * 16 + cl];
        }
        unsigned short* dp = dst + kb * 1024 + cl * 64 + qk * 16;
        *(ushort8v*)(dp) = a;
        *(ushort8v*)(dp + 8) = b;
    }
}

// ---------------- Flash attention: LDS-shared KV, barrier-pipelined ----------
// Block (4 waves) owns a 64-row Q band; wave w = rows band+16w..+15 with a
// COMPLETE output (no cross-wave combine). K/V 64-kv chunks (16KB) staged to
// LDS double-buffer: [barrier; issue stage(c+1); compute(c)] — one barrier
// per chunk; the vmcnt(0) drain at the barrier waits on a load that had the
// whole compute phase to land. Bands paired (b, 31-b): 33 chunks per block,
// uniform over all 512 blocks (2/CU). XCD-pinned (4 bh/XCD).
// LDS granule-16B XOR swizzle (slot = g ^ (row&7)): staging is g2lds16-legal
// (contiguous lane order) AND all ds_read_b128 patterns hit 8 dwords/bank
// (conflict-free). Verified: slot(g^(r&7)) holds g; reader XORs with cl&7.
__global__ __launch_bounds__(256) void attn(const unsigned short* __restrict__ QK,
                                            const unsigned short* __restrict__ V3,
                                            float* __restrict__ Out) {
    const int id = blockIdx.x;
    const int bh = (id & 7) * 4 + ((id >> 3) & 3);     // 4 bh per XCD
    const int pp = id >> 5;                            // band-pair 0..15
    const int t = threadIdx.x;
    const int w = t >> 6;
    const int l = t & 63;
    const int cl = l & 15;
    const int quad = l >> 4;
    const int c7 = cl & 7;

    const size_t bhoff = (size_t)bh * 131072;
    const unsigned short* Qb = QK + bhoff;
    const unsigned short* Kb = QK + (size_t)4194304 + bhoff;
    const unsigned short* Vb = V3 + bhoff;
    float* Ob = Out + bhoff;

    __shared__ unsigned short KVs[2][8192];            // per buf: K 4096 | V 4096

    // --- staging constants (per thread, fixed across chunks) ---
    // K chunk: 64 rows x 128B; slot granule sg -> row sg>>3, holds global
    // granule (sg&7)^(row&7). V chunk: 4 blocks x 1024 shorts; within-block
    // slot wg holds global granule wg^((wg>>3)&7).
    const int sg0 = t, sg1 = 256 + t;
    const int kO0 = (sg0 >> 3) * 64 + (((sg0 & 7) ^ ((sg0 >> 3) & 7)) * 8);
    const int kO1 = (sg1 >> 3) * 64 + (((sg1 & 7) ^ ((sg1 >> 3) & 7)) * 8);
    const int wg0 = sg0 & 63, wg1 = sg1 & 63;
    const int vO0 = (sg0 >> 6) * 512 + ((wg0 ^ ((wg0 >> 3) & 7)) * 8);
    const int vO1 = (sg1 >> 6) * 512 + ((wg1 ^ ((wg1 >> 3) & 7)) * 8);
    const int lB0 = w * 512;                           // shorts (wave-uniform)
    const int lB1 = 2048 + w * 512;

    // --- read offsets (shorts, fixed) ---
    const int oK0 = cl * 64 + (((quad)     ^ c7) * 8);
    const int oK1 = cl * 64 + (((quad + 4) ^ c7) * 8);
    const int oV0 = cl * 64 + (((quad * 2)     ^ c7) * 8);
    const int oV1 = cl * 64 + (((quad * 2 + 1) ^ c7) * 8);

    const int mrel = w * 16 + cl;                      // diag-chunk row rel. base

    #pragma unroll 1                                   // R6 lesson: no state merge
    for (int hb = 0; hb < 2; ++hb) {
        const int bb = hb ? (31 - pp) : pp;            // 64-row band index
        const int m0 = bb * 64 + w * 16;
        const int nch = bb + 1;                        // 64-kv chunks

        bf16x8 qf0, qf1;
        {
            const unsigned short* qa = Qb + (size_t)(m0 + cl) * 64 + quad * 8;
            qf0 = *(const bf16x8*)(qa);
            qf1 = *(const bf16x8*)(qa + 32);
        }

        f32x4 o[4] = {};
        float lps = 0.f;

        // stage chunk 0 into buf 0
        {
            unsigned short* s = &KVs[0][0];
            g2lds16(Kb + kO0, s + lB0);
            g2lds16(Kb + kO1, s + lB1);
            g2lds16(Vb + vO0, s + 4096 + lB0);
            g2lds16(Vb + vO1, s + 4096 + lB1);
        }

        for (int c = 0; c < nch; ++c) {
            __syncthreads();                           // buf[c&1] ready
            if (c + 1 < nch) {                         // prefetch next chunk
                const unsigned short* kg = Kb + (size_t)(c + 1) * 4096;
                const unsigned short* vg = Vb + (size_t)(c + 1) * 4096;
                unsigned short* s = &KVs[(c + 1) & 1][0];
                g2lds16(kg + kO0, s + lB0);
                g2lds16(kg + kO1, s + lB1);
                g2lds16(vg + vO0, s + 4096 + lB0);
                g2lds16(vg + vO1, s + 4096 + lB1);
            }
            const unsigned short* Kl = &KVs[c & 1][0];
            const unsigned short* Vl = Kl + 4096;
            const bool masked = (c == nch - 1) && (hb == 0 ? true : true) && (c == bb);

            // S^T tiles: lane holds (kv = kt*16 + quad*4 + r, m = m0 + cl)
            bf16x8 kf0[4], kf1[4];
            #pragma unroll
            for (int kt = 0; kt < 4; ++kt) {
                kf0[kt] = *(const bf16x8*)(Kl + kt * 1024 + oK0);
                kf1[kt] = *(const bf16x8*)(Kl + kt * 1024 + oK1);
            }
            f32x4 st[4] = {};
            #pragma unroll
            for (int kt = 0; kt < 4; ++kt) {
                st[kt] = __builtin_amdgcn_mfma_f32_16x16x32_bf16(kf0[kt], qf0, st[kt], 0, 0, 0);
                st[kt] = __builtin_amdgcn_mfma_f32_16x16x32_bf16(kf1[kt], qf1, st[kt], 0, 0, 0);
            }

            short4v pb[4];
            #pragma unroll
            for (int kt = 0; kt < 4; ++kt) {
                float p0, p1, p2, p3;
                if (masked) {
                    const int lk = kt * 16 + quad * 4;
                    p0 = (lk     <= mrel) ? E2(st[kt][0]) : 0.f;
                    p1 = (lk + 1 <= mrel) ? E2(st[kt][1]) : 0.f;
                    p2 = (lk + 2 <= mrel) ? E2(st[kt][2]) : 0.f;
                    p3 = (lk + 3 <= mrel) ? E2(st[kt][3]) : 0.f;
                } else {
                    p0 = E2(st[kt][0]);
                    p1 = E2(st[kt][1]);
                    p2 = E2(st[kt][2]);
                    p3 = E2(st[kt][3]);
                }
                lps += (p0 + p1) + (p2 + p3);
                uint2 u = { pk2bf(p0, p1), pk2bf(p2, p3) };
                short4v pv;
                __builtin_memcpy(&pv, &u, 8);
                pb[kt] = pv;
            }

            // O^T += V^T(dt,kt) . P^T(kt)   (16x16x16, K=16)
            #pragma unroll
            for (int kt = 0; kt < 4; ++kt) {
                short8v v0 = *(const short8v*)(Vl + kt * 1024 + oV0);  // dt 0,1
                short8v v1 = *(const short8v*)(Vl + kt * 1024 + oV1);  // dt 2,3
                short4v a0 = __builtin_shufflevector(v0, v0, 0, 1, 2, 3);
                short4v a1 = __builtin_shufflevector(v0, v0, 4, 5, 6, 7);
                short4v a2 = __builtin_shufflevector(v1, v1, 0, 1, 2, 3);
                short4v a3 = __builtin_shufflevector(v1, v1, 4, 5, 6, 7);
                o[0] = __builtin_amdgcn_mfma_f32_16x16x16bf16_1k(a0, pb[kt], o[0], 0, 0, 0);
                o[1] = __builtin_amdgcn_mfma_f32_16x16x16bf16_1k(a1, pb[kt], o[1], 0, 0, 0);
                o[2] = __builtin_amdgcn_mfma_f32_16x16x16bf16_1k(a2, pb[kt], o[2], 0, 0, 0);
                o[3] = __builtin_amdgcn_mfma_f32_16x16x16bf16_1k(a3, pb[kt], o[3], 0, 0, 0);
            }
        }
        __syncthreads();                               // buf reuse across bands

        // row-sum over quads (kv split across quad only), then write.
        // Output lane mapping: m = m0 + cl, d = dt*16 + quad*4 + r.
        lps += __shfl_xor(lps, 16);
        lps += __shfl_xor(lps, 32);
        const float inv = 1.0f / lps;
        #pragma unroll
        for (int dt = 0; dt < 4; ++dt) {
            f32x4 r = o[dt];
            r[0] *= inv; r[1] *= inv; r[2] *= inv; r[3] *= inv;
            *(f32x4*)(Ob + (size_t)(m0 + cl) * 64 + dt * 16 + quad * 4) = r;
        }
    }
}

extern "C" void kernel_launch(void* const* d_in, const int* in_sizes, int n_in,
                              void* d_out, int out_size, void* d_ws, size_t ws_size,
                              hipStream_t stream) {
    const float* x  = (const float*)d_in[0];
    const float* Wq = (const float*)d_in[1];
    const float* Wk = (const float*)d_in[2];
    const float* Wv = (const float*)d_in[3];
    float* out = (float*)d_out;

    // ws: xb 8MB | wc 6MB | QKV natural 24MB | VT3 8MB = 46MB
    unsigned short* xb  = (unsigned short*)d_ws;
    unsigned short* wc  = xb + (size_t)4096 * 1024;
    unsigned short* qkv = wc + (size_t)3 * 1024 * 1024;
    unsigned short* vt  = qkv + (size_t)3 * 4096 * 1024;

    hipLaunchKernelGGL(cast_all, dim3(7168), dim3(256), 0, stream, x, Wq, Wk, Wv, xb, wc);
    hipLaunchKernelGGL(gemm_qkv, dim3(8, 32, 3), dim3(256), 0, stream, xb, wc, qkv);
    hipLaunchKernelGGL(vtrans, dim3(16, 32), dim3(256), 0, stream, qkv + (size_t)2 * 4096 * 1024, vt);
    hipLaunchKernelGGL(attn, dim3(512), dim3(256), 0, stream, qkv, vt, out);
}